// Round 8
// baseline (30.003 us; speedup 1.0000x reference)
//
#include <hip/hip_runtime.h>

#define DD 256
#define TQ 512
#define TK 1024
#define C2 2.88539008177792681472f   // 2*log2(e)

__device__ __forceinline__ float fexp2(float x){ return __builtin_amdgcn_exp2f(x); }
__device__ __forceinline__ float frcp (float x){ return __builtin_amdgcn_rcpf(x); }

// -------- proj: out[r][c] = exp2( C2 * sum_d X[r][d] * W[c][d] ) --------
// tile 32 rows x 32 cols, 1024 threads = 16 waves = 8 d-groups x 2 row-halves.
// Each lane: 2 rows x 4 cols. d-major LDS stride 36 (conflict-free).
// grid (8, 48): by<16 -> query tiles (Eq), else key tiles (Ek).
__global__ __launch_bounds__(1024, 8) void proj_kernel(
    const float* __restrict__ query, const float* __restrict__ key,
    const float* __restrict__ Wq, const float* __restrict__ Wk,
    float* __restrict__ eqo, float* __restrict__ eko)
{
    __shared__ float smem[18432];
    float* Xs = smem;            // [256][36]: Xs[d*36 + r], r<32
    float* Ws = smem + 9216;     // [256][36]: Ws[d*36 + c], c<32

    int by = blockIdx.y;
    const float* X; const float* W; float* out;
    if (by < 16) { X = query; W = Wq; out = eqo; }
    else { by -= 16; X = key; W = Wk; out = eko; }
    const int r0 = by * 32, c0 = blockIdx.x * 32;
    const int tid = threadIdx.x;

    {
        int f = tid;
        #pragma unroll
        for (int rep = 0; rep < 2; ++rep, f += 1024) {
            int row = f & 31, d4 = (f >> 5) << 2;
            float4 xv = *(const float4*)&X[(r0 + row) * DD + d4];
            Xs[(d4 + 0) * 36 + row] = xv.x;
            Xs[(d4 + 1) * 36 + row] = xv.y;
            Xs[(d4 + 2) * 36 + row] = xv.z;
            Xs[(d4 + 3) * 36 + row] = xv.w;
            float4 wv = *(const float4*)&W[(c0 + row) * DD + d4];
            Ws[(d4 + 0) * 36 + row] = wv.x;
            Ws[(d4 + 1) * 36 + row] = wv.y;
            Ws[(d4 + 2) * 36 + row] = wv.z;
            Ws[(d4 + 3) * 36 + row] = wv.w;
        }
    }
    __syncthreads();

    const int w = tid >> 6, t = tid & 63;
    const int g = w >> 1, h = w & 1;         // d-group 0..7, row-half 0..1
    const int rp2 = h * 16 + (t >> 3) * 2;   // 2 rows
    const int cx4 = (t & 7) * 4;             // 4 cols
    float a[2][4] = {{0.f,0.f,0.f,0.f},{0.f,0.f,0.f,0.f}};

    const int dbase = g * 32;
    #pragma unroll 4
    for (int d = dbase; d < dbase + 32; ++d) {
        float2 x2 = *(const float2*)&Xs[d * 36 + rp2];
        float4 w4 = *(const float4*)&Ws[d * 36 + cx4];
        float ww[4] = {w4.x, w4.y, w4.z, w4.w};
        #pragma unroll
        for (int j = 0; j < 4; ++j) {
            a[0][j] = fmaf(x2.x, ww[j], a[0][j]);
            a[1][j] = fmaf(x2.y, ww[j], a[1][j]);
        }
    }

    __syncthreads();   // all reads of Xs/Ws done; safe to alias as reduction buf
    float* red = smem;
    if (g > 0) {
        int base = ((g - 1) * 128 + h * 64 + t) * 9;   // stride 9: conflict-free
        #pragma unroll
        for (int i = 0; i < 2; ++i)
            #pragma unroll
            for (int j = 0; j < 4; ++j) red[base + i * 4 + j] = a[i][j];
    }
    __syncthreads();
    if (g == 0) {
        #pragma unroll
        for (int p = 0; p < 7; ++p) {
            int base = (p * 128 + h * 64 + t) * 9;
            #pragma unroll
            for (int i = 0; i < 2; ++i)
                #pragma unroll
                for (int j = 0; j < 4; ++j) a[i][j] += red[base + i * 4 + j];
        }
        #pragma unroll
        for (int i = 0; i < 2; ++i) {
            float4 s = make_float4(fexp2(C2 * a[i][0]), fexp2(C2 * a[i][1]),
                                   fexp2(C2 * a[i][2]), fexp2(C2 * a[i][3]));
            *(float4*)&out[(r0 + rp2 + i) * DD + c0 + cx4] = s;
        }
    }
}

// -------- scores: out[q][k] = vsum - 2 * sum_d v[d] / (Eq[q][d]*Ek[k][d] + 1) --------
// tile 32 q x 32 k, 1024 threads = 16 waves = 8 d-groups x 2 q-halves.
// Each lane: 2 q-rows x 4 k-cols; quad common denominator: 1 rcp per 4 d-terms.
// d-major LDS stride 36 (conflict-free b64/b128 reads).
__global__ __launch_bounds__(1024, 8) void scores_kernel(
    const float* __restrict__ eqg, const float* __restrict__ ekg,
    const float* __restrict__ v, float* __restrict__ out)
{
    __shared__ float smem[18690];
    float* eq = smem;            // [256][36]: eq[d*36 + r], r<32
    float* ek = smem + 9216;     // [256][36]: ek[d*36 + c], c<32
    float* vs = smem + 18432;    // [256]
    // vsum at smem[18688]; reduction buffer aliases smem[0..8063] after loop

    const int qb = blockIdx.y, kb = blockIdx.x;
    const int tid = threadIdx.x;

    {
        int f = tid;
        #pragma unroll
        for (int rep = 0; rep < 2; ++rep, f += 1024) {
            int row = f & 31, d4 = (f >> 5) << 2;
            float4 qv = *(const float4*)&eqg[(qb * 32 + row) * DD + d4];
            eq[(d4 + 0) * 36 + row] = qv.x;
            eq[(d4 + 1) * 36 + row] = qv.y;
            eq[(d4 + 2) * 36 + row] = qv.z;
            eq[(d4 + 3) * 36 + row] = qv.w;
            float4 kv = *(const float4*)&ekg[(kb * 32 + row) * DD + d4];
            ek[(d4 + 0) * 36 + row] = kv.x;
            ek[(d4 + 1) * 36 + row] = kv.y;
            ek[(d4 + 2) * 36 + row] = kv.z;
            ek[(d4 + 3) * 36 + row] = kv.w;
        }
        if (tid < 64) {
            float4 vv = *(const float4*)&v[tid * 4];
            *(float4*)&vs[tid * 4] = vv;
            float s = vv.x + vv.y + vv.z + vv.w;
            #pragma unroll
            for (int m = 1; m < 64; m <<= 1) s += __shfl_xor(s, m);
            if (tid == 0) smem[18688] = s;
        }
    }
    __syncthreads();

    const int w = tid >> 6, t = tid & 63;
    const int g = w >> 1, h = w & 1;         // d-group 0..7, q-half 0..1
    const int qp2 = h * 16 + (t >> 3) * 2;   // 2 q-rows
    const int kq4 = (t & 7) * 4;             // 4 k-cols
    float a[2][4] = {{0.f,0.f,0.f,0.f},{0.f,0.f,0.f,0.f}};

    const int dbase = g * 32;
    #pragma unroll 2
    for (int s = 0; s < 8; ++s) {
        const int d0 = dbase + s * 4;
        float4 v4 = *(const float4*)&vs[d0];
        float Qr[4][2], Kr[4][4];            // [di][idx], all-constant indexing
        #pragma unroll
        for (int di = 0; di < 4; ++di) {
            float2 q2 = *(const float2*)&eq[(d0 + di) * 36 + qp2];
            Qr[di][0] = q2.x; Qr[di][1] = q2.y;
            float4 k4 = *(const float4*)&ek[(d0 + di) * 36 + kq4];
            Kr[di][0] = k4.x; Kr[di][1] = k4.y; Kr[di][2] = k4.z; Kr[di][3] = k4.w;
        }
        #pragma unroll
        for (int i = 0; i < 2; ++i) {
            #pragma unroll
            for (int j = 0; j < 4; ++j) {
                float t0 = fmaf(Qr[0][i], Kr[0][j], 1.f);
                float t1 = fmaf(Qr[1][i], Kr[1][j], 1.f);
                float t2 = fmaf(Qr[2][i], Kr[2][j], 1.f);
                float t3 = fmaf(Qr[3][i], Kr[3][j], 1.f);
                float A  = t0 * t1;
                float B  = t2 * t3;
                float den = A * B;
                float n01 = fmaf(v4.x, t1, v4.y * t0);
                float n23 = fmaf(v4.z, t3, v4.w * t2);
                float num = fmaf(n01, B, n23 * A);
                a[i][j] = fmaf(num, frcp(den), a[i][j]);
            }
        }
    }

    __syncthreads();   // all reads of eq/ek done; safe to alias as reduction buf
    float* red = smem;
    if (g > 0) {
        int base = ((g - 1) * 128 + h * 64 + t) * 9;   // stride 9: conflict-free
        #pragma unroll
        for (int i = 0; i < 2; ++i)
            #pragma unroll
            for (int j = 0; j < 4; ++j) red[base + i * 4 + j] = a[i][j];
    }
    __syncthreads();
    if (g == 0) {
        #pragma unroll
        for (int p = 0; p < 7; ++p) {
            int base = (p * 128 + h * 64 + t) * 9;
            #pragma unroll
            for (int i = 0; i < 2; ++i)
                #pragma unroll
                for (int j = 0; j < 4; ++j) a[i][j] += red[base + i * 4 + j];
        }
        float vsum = smem[18688];
        const int row0 = qb * 32 + qp2, col = kb * 32 + kq4;
        #pragma unroll
        for (int i = 0; i < 2; ++i) {
            float4 s = make_float4(fmaf(-2.f, a[i][0], vsum), fmaf(-2.f, a[i][1], vsum),
                                   fmaf(-2.f, a[i][2], vsum), fmaf(-2.f, a[i][3], vsum));
            *(float4*)&out[(row0 + i) * TK + col] = s;
        }
    }
}

extern "C" void kernel_launch(void* const* d_in, const int* in_sizes, int n_in,
                              void* d_out, int out_size, void* d_ws, size_t ws_size,
                              hipStream_t stream) {
    const float* query = (const float*)d_in[0];   // [512,256]
    const float* key   = (const float*)d_in[1];   // [1024,256]
    // d_in[2] = value, unused by the reference
    const float* Wq    = (const float*)d_in[3];   // [256,256]
    const float* Wk    = (const float*)d_in[4];   // [256,256]
    const float* vw    = (const float*)d_in[5];   // [1,256]
    float* out = (float*)d_out;                   // [512,1024]

    float* eq = (float*)d_ws;                     // 512*256 f32
    float* ek = eq + TQ * DD;                     // 1024*256 f32

    proj_kernel<<<dim3(8, 48), 1024, 0, stream>>>(query, key, Wq, Wk, eq, ek);
    scores_kernel<<<dim3(TK / 32, TQ / 32), 1024, 0, stream>>>(eq, ek, vw, out);
}